// Round 3
// baseline (877.510 us; speedup 1.0000x reference)
//
#include <hip/hip_runtime.h>

#define N_NODES 100000
#define N_EDGES 1600000
#define IN_C    128
#define HID     256
#define NLAYER  4

#define NBUCK 391     // ceil(N_NODES / 256) buckets, bucket = col >> 8
#define BCAP  8192    // padded per-bucket capacity in pairs buffer
#define EPB   4096    // edges per kb_scatter block
#define CAPL  6144    // per-bucket LDS srcl capacity in kb_build

typedef __attribute__((ext_vector_type(8))) __bf16 bf16x8;
typedef __attribute__((ext_vector_type(4))) float  floatx4;
typedef __attribute__((ext_vector_type(2))) float  floatx2;

__device__ inline unsigned short f2b(float f) {
    unsigned u = __builtin_bit_cast(unsigned, f);
    return (unsigned short)((u + 0x7fffu + ((u >> 16) & 1u)) >> 16);
}
// packed fp32 add (VOP3P)
__device__ inline floatx2 pkadd(floatx2 x, floatx2 y) {
    floatx2 r;
    asm("v_pk_add_f32 %0, %1, %2" : "=v"(r) : "v"(x), "v"(y));
    return r;
}
// unpack+accumulate 8 bf16 (uint4) into 4 packed fp32 pairs
__device__ inline void acc8p(floatx2* a, uint4 v) {
    unsigned wds[4] = {v.x, v.y, v.z, v.w};
    #pragma unroll
    for (int k = 0; k < 4; ++k) {
        floatx2 x;
        x[0] = __builtin_bit_cast(float, wds[k] << 16);
        x[1] = __builtin_bit_cast(float, wds[k] & 0xffff0000u);
        a[k] = pkadd(a[k], x);
    }
}
// async global->LDS, 16 B per lane (lane-contiguous LDS dest required)
__device__ inline void gl16(const void* g, void* l) {
    __builtin_amdgcn_global_load_lds(
        (const __attribute__((address_space(1))) unsigned int*)g,
        (__attribute__((address_space(3))) unsigned int*)l, 16, 0, 0);
}

// ---------------- CSR build: bucket pipeline ----------------
__global__ __launch_bounds__(256) void kb_scatter(
        const int* __restrict__ row, const int* __restrict__ col,
        int* __restrict__ gfill, unsigned* __restrict__ pairs, int e) {
    __shared__ unsigned sp[EPB];            // bucket-sorted packed (src<<8 | col&255)
    __shared__ unsigned short sbk[EPB];     // bucket id per sorted element
    __shared__ int hist[NBUCK];
    __shared__ int lpre[NBUCK];
    __shared__ int lbase[NBUCK];
    __shared__ int wsum[4];
    __shared__ int carry;
    const int tid = threadIdx.x, lane = tid & 63, w = tid >> 6;
    const int base = blockIdx.x * EPB;
    const int nv   = min(EPB, e - base);
    for (int b = tid; b < NBUCK; b += 256) hist[b] = 0;
    __syncthreads();
    #pragma unroll
    for (int k = 0; k < EPB / 256; ++k) {
        int i = base + k * 256 + tid;
        if (i < e) atomicAdd(&hist[((unsigned)col[i]) >> 8], 1);
    }
    __syncthreads();
    for (int b = tid; b < NBUCK; b += 256) {
        int h = hist[b];
        lbase[b] = h ? atomicAdd(&gfill[b], h) : 0;
    }
    {
        int v = hist[tid];
        int inc = v;
        #pragma unroll
        for (int o = 1; o < 64; o <<= 1) { int u = __shfl_up(inc, o); if (lane >= o) inc += u; }
        if (lane == 63) wsum[w] = inc;
        __syncthreads();
        if (tid == 0) { int r = 0; for (int i = 0; i < 4; ++i) { int x = wsum[i]; wsum[i] = r; r += x; } carry = r; }
        __syncthreads();
        lpre[tid] = wsum[w] + inc - v;
        int c0 = carry;
        __syncthreads();
        int idx = 256 + tid;
        int v1 = (idx < NBUCK) ? hist[idx] : 0;
        int inc1 = v1;
        #pragma unroll
        for (int o = 1; o < 64; o <<= 1) { int u = __shfl_up(inc1, o); if (lane >= o) inc1 += u; }
        if (lane == 63) wsum[w] = inc1;
        __syncthreads();
        if (tid == 0) { int r = 0; for (int i = 0; i < 4; ++i) { int x = wsum[i]; wsum[i] = r; r += x; } }
        __syncthreads();
        if (idx < NBUCK) lpre[idx] = c0 + wsum[w] + inc1 - v1;
    }
    __syncthreads();
    for (int b = tid; b < NBUCK; b += 256) hist[b] = 0;   // reuse as fill counters
    __syncthreads();
    #pragma unroll
    for (int k = 0; k < EPB / 256; ++k) {
        int i = base + k * 256 + tid;
        if (i < e) {
            unsigned cv = (unsigned)col[i];
            int bk = cv >> 8;
            int q = lpre[bk] + atomicAdd(&hist[bk], 1);
            sp[q]  = ((unsigned)row[i] << 8) | (cv & 255u);
            sbk[q] = (unsigned short)bk;
        }
    }
    __syncthreads();
    for (int i = tid; i < nv; i += 256) {
        int bk = sbk[i];
        int pos = lbase[bk] + (i - lpre[bk]);
        if (pos < BCAP) pairs[(size_t)bk * BCAP + pos] = sp[i];
    }
}

__global__ __launch_bounds__(256) void kb_build(
        const unsigned* __restrict__ pairs, const int* __restrict__ gfill,
        int* __restrict__ offs, float* __restrict__ dis,
        int* __restrict__ srcl, int n) {
    __shared__ int lcnt[256];
    __shared__ int lstart[256];
    __shared__ int wsum[4];
    __shared__ int sbase;
    __shared__ int sl[CAPL];
    const int b = blockIdx.x;
    const int tid = threadIdx.x, lane = tid & 63, w = tid >> 6;
    int cnt = gfill[b]; if (cnt > CAPL) cnt = CAPL;
    const unsigned* bp = pairs + (size_t)b * BCAP;
    int pa = 0;
    for (int i = tid; i < b; i += 256) pa += gfill[i];
    #pragma unroll
    for (int o = 1; o < 64; o <<= 1) pa += __shfl_xor(pa, o);
    lcnt[tid] = 0;
    if (lane == 0) wsum[w] = pa;
    __syncthreads();
    if (tid == 0) sbase = wsum[0] + wsum[1] + wsum[2] + wsum[3];
    for (int i = tid; i < cnt; i += 256)
        atomicAdd(&lcnt[bp[i] & 255u], 1);
    __syncthreads();
    const int base = sbase;
    int v = lcnt[tid];
    int inc = v;
    #pragma unroll
    for (int o = 1; o < 64; o <<= 1) { int u = __shfl_up(inc, o); if (lane >= o) inc += u; }
    if (lane == 63) wsum[w] = inc;
    __syncthreads();
    if (tid == 0) { int r = 0; for (int i = 0; i < 4; ++i) { int x = wsum[i]; wsum[i] = r; r += x; } }
    __syncthreads();
    int excl = wsum[w] + inc - v;
    lstart[tid] = excl;
    int node = (b << 8) + tid;
    if (node < n) {
        dis[node]  = rsqrtf((float)(v + 1));   // +1 self-loop
        offs[node] = base + excl;
    }
    __syncthreads();
    lcnt[tid] = 0;   // reuse as fill counters
    __syncthreads();
    for (int i = tid; i < cnt; i += 256) {
        unsigned pr = bp[i];
        int c = pr & 255u;
        int q = lstart[c] + atomicAdd(&lcnt[c], 1);
        sl[q] = (int)(pr >> 8);
    }
    __syncthreads();
    for (int i = tid; i < cnt; i += 256)
        srcl[base + i] = sl[i];
}

// ---------------- merged: zero gfill + offs sentinel + weight transpose/convert ----------------
__global__ void k_wtz(const float* __restrict__ enc_w, const float* __restrict__ conv_w,
                      const float* __restrict__ w1,
                      unsigned short* __restrict__ enc_t, unsigned short* __restrict__ conv_t,
                      unsigned short* __restrict__ lin1_t, int* __restrict__ gfill,
                      int* __restrict__ offs) {
    int idx = blockIdx.x * blockDim.x + threadIdx.x;
    if (idx == 0) offs[N_NODES] = N_EDGES;
    if (idx < NBUCK) gfill[idx] = 0;
    if (idx < IN_C * HID) {
        int k = idx / HID, n = idx % HID;
        enc_t[n * IN_C + k] = f2b(enc_w[idx]);
    } else if (idx < IN_C * HID + NLAYER * HID * HID) {
        int r = idx - IN_C * HID;
        int l = r / (HID * HID);
        int e = r % (HID * HID);
        int k = e / HID, n = e % HID;
        conv_t[(size_t)l * HID * HID + n * HID + k] = f2b(conv_w[r]);
    } else if (idx < IN_C * HID + NLAYER * HID * HID + HID * (HID / 2)) {
        int e = idx - (IN_C * HID + NLAYER * HID * HID);
        int k = e / (HID / 2), n = e % (HID / 2);
        lin1_t[n * HID + k] = f2b(w1[e]);
    }
}

// ---------------- encoder GEMM: hb = bf16(x(fp32) @ enc_t^T + bias) ----------------
__global__ __launch_bounds__(512) void k_mme(
        const float* __restrict__ Af,
        const unsigned short* __restrict__ Wt,     // [256][128]
        const float* __restrict__ bias,
        unsigned short* __restrict__ Cout, int M) {
    const int K = IN_C;                            // 128
    __shared__ unsigned short As[128 * 32];
    __shared__ unsigned short Bs[256 * 32];
    const int tid  = threadIdx.x;
    const int lane = tid & 63;
    const int w    = tid >> 6;
    const int bm   = blockIdx.x * 128;

    const int r0 = tid >> 2, q0 = tid & 3;
    const int a_off  = min(bm + r0, M - 1) * K + q0 * 8;
    const int b_off0 = r0 * K + q0 * 8;
    const int b_off1 = (r0 + 128) * K + q0 * 8;

    floatx4 acc[4][4];
    #pragma unroll
    for (int i = 0; i < 4; ++i)
        #pragma unroll
        for (int j = 0; j < 4; ++j)
            acc[i][j] = (floatx4){0.f, 0.f, 0.f, 0.f};

    const int wm = (w & 1) * 64;
    const int wn = (w >> 1) * 64;
    const int fm = lane & 15;
    const int fq = (lane >> 4) * 8;

    uint4 ra;
    auto loadA = [&](int koff, uint4& oa) {
        float4 f0 = *(const float4*)(Af + a_off + koff);
        float4 f1 = *(const float4*)(Af + a_off + koff + 4);
        oa.x = (unsigned)f2b(f0.x) | ((unsigned)f2b(f0.y) << 16);
        oa.y = (unsigned)f2b(f0.z) | ((unsigned)f2b(f0.w) << 16);
        oa.z = (unsigned)f2b(f1.x) | ((unsigned)f2b(f1.y) << 16);
        oa.w = (unsigned)f2b(f1.z) | ((unsigned)f2b(f1.w) << 16);
    };

    loadA(0, ra);

    const int KT = K >> 5;   // 4
    for (int kt = 0; kt < KT; ++kt) {
        int k0 = kt << 5;
        ((uint4*)As)[tid] = ra;
        gl16(Wt + b_off0 + k0, Bs + (size_t)tid * 8);
        gl16(Wt + b_off1 + k0, Bs + (size_t)(tid + 512) * 8);
        __syncthreads();
        if (kt + 1 < KT) loadA((kt + 1) << 5, ra);
        bf16x8 af[4], bfr[4];
        #pragma unroll
        for (int i = 0; i < 4; ++i)
            af[i] = *(const bf16x8*)(const void*)(As + (wm + i * 16 + fm) * 32 + fq);
        #pragma unroll
        for (int j = 0; j < 4; ++j)
            bfr[j] = *(const bf16x8*)(const void*)(Bs + (wn + j * 16 + fm) * 32 + fq);
        #pragma unroll
        for (int i = 0; i < 4; ++i)
            #pragma unroll
            for (int j = 0; j < 4; ++j)
                acc[i][j] = __builtin_amdgcn_mfma_f32_16x16x32_bf16(af[i], bfr[j], acc[i][j], 0, 0, 0);
        __syncthreads();
    }

    const int quad = lane >> 4;
    #pragma unroll
    for (int i = 0; i < 4; ++i) {
        #pragma unroll
        for (int r = 0; r < 4; ++r) {
            int row = bm + wm + i * 16 + quad * 4 + r;
            if (row >= M) continue;
            #pragma unroll
            for (int j = 0; j < 4; ++j) {
                int colg = wn + j * 16 + fm;
                float v = acc[i][j][r] + bias[colg];
                Cout[(size_t)row * HID + colg] = f2b(v);
            }
        }
    }
}

// ---------------- conv GEMM (bf16): hw = bf16((h @ W) * scale[row]) ----------------
__global__ __launch_bounds__(512) void k_mmc(
        const unsigned short* __restrict__ A,      // [M][256] bf16
        const unsigned short* __restrict__ Wt,     // [256][256] bf16
        const float* __restrict__ scale,
        unsigned short* __restrict__ Cout, int M) {
    const int K = HID;                             // 256
    __shared__ unsigned short As[128 * 32];
    __shared__ unsigned short Bs[256 * 32];
    const int tid  = threadIdx.x;
    const int lane = tid & 63;
    const int w    = tid >> 6;
    const int bm   = blockIdx.x * 128;

    const int r0 = tid >> 2, q0 = tid & 3;
    const int a_off  = min(bm + r0, M - 1) * K + q0 * 8;
    const int b_off0 = r0 * K + q0 * 8;
    const int b_off1 = (r0 + 128) * K + q0 * 8;

    floatx4 acc[4][4];
    #pragma unroll
    for (int i = 0; i < 4; ++i)
        #pragma unroll
        for (int j = 0; j < 4; ++j)
            acc[i][j] = (floatx4){0.f, 0.f, 0.f, 0.f};

    const int wm = (w & 1) * 64;
    const int wn = (w >> 1) * 64;
    const int fm = lane & 15;
    const int fq = (lane >> 4) * 8;

    for (int kt = 0; kt < 8; ++kt) {
        int k0 = kt << 5;
        gl16(A  + a_off  + k0, As + (size_t)tid * 8);
        gl16(Wt + b_off0 + k0, Bs + (size_t)tid * 8);
        gl16(Wt + b_off1 + k0, Bs + (size_t)(tid + 512) * 8);
        __syncthreads();
        bf16x8 af[4], bfr[4];
        #pragma unroll
        for (int i = 0; i < 4; ++i)
            af[i] = *(const bf16x8*)(const void*)(As + (wm + i * 16 + fm) * 32 + fq);
        #pragma unroll
        for (int j = 0; j < 4; ++j)
            bfr[j] = *(const bf16x8*)(const void*)(Bs + (wn + j * 16 + fm) * 32 + fq);
        #pragma unroll
        for (int i = 0; i < 4; ++i)
            #pragma unroll
            for (int j = 0; j < 4; ++j)
                acc[i][j] = __builtin_amdgcn_mfma_f32_16x16x32_bf16(af[i], bfr[j], acc[i][j], 0, 0, 0);
        __syncthreads();
    }

    const int quad = lane >> 4;
    #pragma unroll
    for (int i = 0; i < 4; ++i) {
        #pragma unroll
        for (int r = 0; r < 4; ++r) {
            int row = bm + wm + i * 16 + quad * 4 + r;
            if (row >= M) continue;
            float sc = scale[row];
            #pragma unroll
            for (int j = 0; j < 4; ++j) {
                int colg = wn + j * 16 + fm;
                Cout[(size_t)row * HID + colg] = f2b(acc[i][j][r] * sc);
            }
        }
    }
}

// ---------------- fused layer: agg+LN+ReLU (LDS) -> GEMM xW*dis -> hwout ----------------
// phase 1: 8 waves, one node/wave/round, 16 rounds -> 128x256 bf16 A-tile in LDS
//          (XOR-swizzled: byte ^= (row&7)<<4 to break the 512 B row-stride bank pattern)
// phase 2: k_mmc-style 128x256x256 GEMM, A from LDS, W staged via global_load_lds
__global__ __launch_bounds__(512, 4) void k_fused(
        const unsigned short* __restrict__ hwin, const int* __restrict__ srcl,
        const int* __restrict__ offs, const float* __restrict__ dis,
        const float* __restrict__ cb, const float* __restrict__ g,
        const float* __restrict__ bt,
        const unsigned short* __restrict__ Wt,     // conv_t[l+1] [256][256]
        unsigned short* __restrict__ hwout, int M) {
    __shared__ unsigned short As2[128 * 256];      // 64 KB swizzled A tile
    __shared__ unsigned short Bs[256 * 32];        // 16 KB W k-chunk
    const int tid  = threadIdx.x;
    const int lane = tid & 63;
    const int w    = tid >> 6;                     // 0..7
    const int bm   = blockIdx.x * 128;
    const int half = lane >> 5;
    const int sub  = lane & 31;
    const uint4* T = (const uint4*)hwin;
    const float4* cb4 = (const float4*)cb;
    const float4* g4  = (const float4*)g;
    const float4* bt4 = (const float4*)bt;

    // ---- phase 1: aggregate + bias + LN + ReLU -> As2 ----
    for (int rr = 0; rr < 16; ++rr) {
        const int nloc = rr * 8 + w;
        const int node = bm + nloc;
        if (node < M) {
            floatx2 a2[4], c2[4];
            #pragma unroll
            for (int k = 0; k < 4; ++k) { a2[k] = (floatx2)0.f; c2[k] = (floatx2)0.f; }
            if (half == 0)
                acc8p(a2, T[(size_t)node * 32 + sub]);   // self-loop (pre-scaled)
            int p = offs[node], pe = offs[node + 1];
            if (p + 7 < pe) {
                uint4 va, vb, vc, vd;
                {
                    int s0 = srcl[p],     s1 = srcl[p + 1], s2 = srcl[p + 2], s3 = srcl[p + 3];
                    int s4 = srcl[p + 4], s5 = srcl[p + 5], s6 = srcl[p + 6], s7 = srcl[p + 7];
                    int ea = half ? s1 : s0, eb = half ? s3 : s2;
                    int ec = half ? s5 : s4, ed = half ? s7 : s6;
                    va = T[(size_t)ea * 32 + sub]; vb = T[(size_t)eb * 32 + sub];
                    vc = T[(size_t)ec * 32 + sub]; vd = T[(size_t)ed * 32 + sub];
                }
                for (p += 8; p + 7 < pe; p += 8) {
                    int s0 = srcl[p],     s1 = srcl[p + 1], s2 = srcl[p + 2], s3 = srcl[p + 3];
                    int s4 = srcl[p + 4], s5 = srcl[p + 5], s6 = srcl[p + 6], s7 = srcl[p + 7];
                    int ea = half ? s1 : s0, eb = half ? s3 : s2;
                    int ec = half ? s5 : s4, ed = half ? s7 : s6;
                    uint4 wa = T[(size_t)ea * 32 + sub];
                    uint4 wb = T[(size_t)eb * 32 + sub];
                    uint4 wc = T[(size_t)ec * 32 + sub];
                    uint4 wd = T[(size_t)ed * 32 + sub];
                    acc8p(a2, va); acc8p(c2, vb); acc8p(a2, vc); acc8p(c2, vd);
                    va = wa; vb = wb; vc = wc; vd = wd;
                }
                acc8p(a2, va); acc8p(c2, vb); acc8p(a2, vc); acc8p(c2, vd);
            }
            for (; p + 1 < pe; p += 2) {
                int s0 = srcl[p], s1 = srcl[p + 1];
                int ea = half ? s1 : s0;
                acc8p(a2, T[(size_t)ea * 32 + sub]);
            }
            if (p < pe && half == 0)
                acc8p(a2, T[(size_t)srcl[p] * 32 + sub]);

            float af8[8];
            #pragma unroll
            for (int k = 0; k < 4; ++k) {
                floatx2 t = pkadd(a2[k], c2[k]);
                af8[2 * k]     = t[0] + __shfl_xor(t[0], 32);
                af8[2 * k + 1] = t[1] + __shfl_xor(t[1], 32);
            }
            float dc = dis[node];
            float4 cba = cb4[sub * 2], cbb = cb4[sub * 2 + 1];
            float h[8];
            h[0] = fmaf(af8[0], dc, cba.x); h[1] = fmaf(af8[1], dc, cba.y);
            h[2] = fmaf(af8[2], dc, cba.z); h[3] = fmaf(af8[3], dc, cba.w);
            h[4] = fmaf(af8[4], dc, cbb.x); h[5] = fmaf(af8[5], dc, cbb.y);
            h[6] = fmaf(af8[6], dc, cbb.z); h[7] = fmaf(af8[7], dc, cbb.w);
            float s = 0.f, sq = 0.f;
            #pragma unroll
            for (int j = 0; j < 8; ++j) { s += h[j]; sq += h[j] * h[j]; }
            #pragma unroll
            for (int off = 1; off < 32; off <<= 1) { s += __shfl_xor(s, off); sq += __shfl_xor(sq, off); }
            float mu  = s * (1.f / 256.f);
            float var = sq * (1.f / 256.f) - mu * mu;
            float inv = rsqrtf(var + 1e-5f);
            if (half == 0) {
                float4 ga = g4[sub * 2], gb = g4[sub * 2 + 1];
                float4 ba = bt4[sub * 2], bb = bt4[sub * 2 + 1];
                float gv[8] = {ga.x, ga.y, ga.z, ga.w, gb.x, gb.y, gb.z, gb.w};
                float bv[8] = {ba.x, ba.y, ba.z, ba.w, bb.x, bb.y, bb.z, bb.w};
                unsigned short o[8];
                #pragma unroll
                for (int j = 0; j < 8; ++j)
                    o[j] = f2b(fmaxf(fmaf((h[j] - mu) * inv, gv[j], bv[j]), 0.f));
                uint4 st;
                st.x = (unsigned)o[0] | ((unsigned)o[1] << 16);
                st.y = (unsigned)o[2] | ((unsigned)o[3] << 16);
                st.z = (unsigned)o[4] | ((unsigned)o[5] << 16);
                st.w = (unsigned)o[6] | ((unsigned)o[7] << 16);
                unsigned byte = ((unsigned)(nloc * 512 + sub * 16)) ^ (((unsigned)nloc & 7u) << 4);
                *(uint4*)((char*)As2 + byte) = st;
            }
        }
    }
    __syncthreads();

    // ---- phase 2: GEMM (As2 @ Wt) * dis[row] -> hwout ----
    const int r0 = tid >> 2, q0 = tid & 3;
    const int b_off0 = r0 * 256 + q0 * 8;
    const int b_off1 = (r0 + 128) * 256 + q0 * 8;

    floatx4 acc[4][4];
    #pragma unroll
    for (int i = 0; i < 4; ++i)
        #pragma unroll
        for (int j = 0; j < 4; ++j)
            acc[i][j] = (floatx4){0.f, 0.f, 0.f, 0.f};

    const int wm = (w & 1) * 64;
    const int wn = (w >> 1) * 64;
    const int fm = lane & 15;
    const int fq = (lane >> 4) * 8;

    for (int kt = 0; kt < 8; ++kt) {
        int k0 = kt << 5;
        gl16(Wt + b_off0 + k0, Bs + (size_t)tid * 8);
        gl16(Wt + b_off1 + k0, Bs + (size_t)(tid + 512) * 8);
        __syncthreads();
        bf16x8 af[4], bfr[4];
        #pragma unroll
        for (int i = 0; i < 4; ++i) {
            int row = wm + i * 16 + fm;
            unsigned byte = ((unsigned)(row * 512 + kt * 64 + fq * 2)) ^ (((unsigned)row & 7u) << 4);
            af[i] = *(const bf16x8*)(const void*)((const char*)As2 + byte);
        }
        #pragma unroll
        for (int j = 0; j < 4; ++j)
            bfr[j] = *(const bf16x8*)(const void*)(Bs + (wn + j * 16 + fm) * 32 + fq);
        #pragma unroll
        for (int i = 0; i < 4; ++i)
            #pragma unroll
            for (int j = 0; j < 4; ++j)
                acc[i][j] = __builtin_amdgcn_mfma_f32_16x16x32_bf16(af[i], bfr[j], acc[i][j], 0, 0, 0);
        __syncthreads();
    }

    const int quad = lane >> 4;
    #pragma unroll
    for (int i = 0; i < 4; ++i) {
        #pragma unroll
        for (int r = 0; r < 4; ++r) {
            int row = bm + wm + i * 16 + quad * 4 + r;
            if (row >= M) continue;
            float sc = dis[row];
            #pragma unroll
            for (int j = 0; j < 4; ++j) {
                int colg = wn + j * 16 + fm;
                hwout[(size_t)row * HID + colg] = f2b(acc[i][j][r] * sc);
            }
        }
    }
}

// ---------------- fused head: out = relu(h@w1+b1)@w2 + b2 ----------------
__global__ __launch_bounds__(256) void k_head(
        const unsigned short* __restrict__ A,     // h bf16 [M,256]
        const unsigned short* __restrict__ Wt,    // lin1^T bf16 [128][256]
        const float* __restrict__ b1, const float* __restrict__ w2,
        const float* __restrict__ b2, float* __restrict__ out, int M) {
    const int K = 256;
    __shared__ unsigned short As[128 * 32];
    __shared__ unsigned short Bs[128 * 32];
    const int tid  = threadIdx.x;
    const int lane = tid & 63;
    const int w    = tid >> 6;
    const int bm   = blockIdx.x * 128;

    const int i0 = tid, i1 = tid + 256;
    const int r0 = i0 >> 2, r1 = i1 >> 2;
    const int q0 = i0 & 3,  q1 = i1 & 3;
    const int a_off0 = min(bm + r0, M - 1) * K + q0 * 8;
    const int a_off1 = min(bm + r1, M - 1) * K + q1 * 8;
    const int b_off0 = r0 * K + q0 * 8;
    const int b_off1 = r1 * K + q1 * 8;

    floatx4 acc[4][4];
    #pragma unroll
    for (int i = 0; i < 4; ++i)
        #pragma unroll
        for (int j = 0; j < 4; ++j)
            acc[i][j] = (floatx4){0.f, 0.f, 0.f, 0.f};

    const int wm = (w & 1) * 64;
    const int wn = (w >> 1) * 64;
    const int fm = lane & 15;
    const int fq = (lane >> 4) * 8;

    for (int kt = 0; kt < 8; ++kt) {
        int k0 = kt << 5;
        gl16(A  + a_off0 + k0, As + (size_t)i0 * 8);
        gl16(A  + a_off1 + k0, As + (size_t)i1 * 8);
        gl16(Wt + b_off0 + k0, Bs + (size_t)i0 * 8);
        gl16(Wt + b_off1 + k0, Bs + (size_t)i1 * 8);
        __syncthreads();
        bf16x8 af[4], bfr[4];
        #pragma unroll
        for (int i = 0; i < 4; ++i)
            af[i] = *(const bf16x8*)(const void*)(As + (wm + i * 16 + fm) * 32 + fq);
        #pragma unroll
        for (int j = 0; j < 4; ++j)
            bfr[j] = *(const bf16x8*)(const void*)(Bs + (wn + j * 16 + fm) * 32 + fq);
        #pragma unroll
        for (int i = 0; i < 4; ++i)
            #pragma unroll
            for (int j = 0; j < 4; ++j)
                acc[i][j] = __builtin_amdgcn_mfma_f32_16x16x32_bf16(af[i], bfr[j], acc[i][j], 0, 0, 0);
        __syncthreads();
    }

    float* red = (float*)As;   // 256 floats, safe after final barrier
    const int q = lane >> 4;
    float b1v[4], w2v[4];
    #pragma unroll
    for (int j = 0; j < 4; ++j) {
        int col = wn + j * 16 + fm;
        b1v[j] = b1[col]; w2v[j] = w2[col];
    }
    #pragma unroll
    for (int i = 0; i < 4; ++i) {
        #pragma unroll
        for (int r = 0; r < 4; ++r) {
            float s = 0.f;
            #pragma unroll
            for (int j = 0; j < 4; ++j)
                s += fmaxf(acc[i][j][r] + b1v[j], 0.f) * w2v[j];
            #pragma unroll
            for (int off = 1; off < 16; off <<= 1) s += __shfl_xor(s, off);
            if (fm == 0) {
                int m = wm + i * 16 + q * 4 + r;
                red[m * 2 + (wn >> 6)] = s;
            }
        }
    }
    __syncthreads();
    if (tid < 128) {
        int row = bm + tid;
        if (row < M) out[row] = red[tid * 2] + red[tid * 2 + 1] + b2[0];
    }
}

// ---------------- aggregation + bias + LayerNorm + ReLU (last layer, global out) ----------------
__global__ void k_agg(const unsigned short* __restrict__ hw, const int* __restrict__ srcl,
                      const int* __restrict__ offs, const float* __restrict__ dis,
                      const float* __restrict__ cb, const float* __restrict__ g,
                      const float* __restrict__ bt, unsigned short* __restrict__ hout, int n) {
    int gtid = blockIdx.x * blockDim.x + threadIdx.x;
    int node = __builtin_amdgcn_readfirstlane(gtid >> 6);   // grid sized so node < n always
    int lane = threadIdx.x & 63;
    const int half = lane >> 5;
    const int sub  = lane & 31;
    const uint4* T = (const uint4*)hw;    // row = 32 x uint4 (512 B)

    floatx2 a2[4], c2[4];
    #pragma unroll
    for (int k = 0; k < 4; ++k) { a2[k] = (floatx2)0.f; c2[k] = (floatx2)0.f; }
    if (half == 0)
        acc8p(a2, T[(size_t)node * 32 + sub]);   // self-loop (pre-scaled by dis[src])

    int p = offs[node], pe = offs[node + 1];
    if (p + 7 < pe) {
        uint4 va, vb, vc, vd;
        {
            int s0 = srcl[p],     s1 = srcl[p + 1], s2 = srcl[p + 2], s3 = srcl[p + 3];
            int s4 = srcl[p + 4], s5 = srcl[p + 5], s6 = srcl[p + 6], s7 = srcl[p + 7];
            int ea = half ? s1 : s0, eb = half ? s3 : s2;
            int ec = half ? s5 : s4, ed = half ? s7 : s6;
            va = T[(size_t)ea * 32 + sub]; vb = T[(size_t)eb * 32 + sub];
            vc = T[(size_t)ec * 32 + sub]; vd = T[(size_t)ed * 32 + sub];
        }
        for (p += 8; p + 7 < pe; p += 8) {
            int s0 = srcl[p],     s1 = srcl[p + 1], s2 = srcl[p + 2], s3 = srcl[p + 3];
            int s4 = srcl[p + 4], s5 = srcl[p + 5], s6 = srcl[p + 6], s7 = srcl[p + 7];
            int ea = half ? s1 : s0, eb = half ? s3 : s2;
            int ec = half ? s5 : s4, ed = half ? s7 : s6;
            uint4 wa = T[(size_t)ea * 32 + sub];
            uint4 wb = T[(size_t)eb * 32 + sub];
            uint4 wc = T[(size_t)ec * 32 + sub];
            uint4 wd = T[(size_t)ed * 32 + sub];
            acc8p(a2, va); acc8p(c2, vb); acc8p(a2, vc); acc8p(c2, vd);
            va = wa; vb = wb; vc = wc; vd = wd;
        }
        acc8p(a2, va); acc8p(c2, vb); acc8p(a2, vc); acc8p(c2, vd);
    }
    for (; p + 1 < pe; p += 2) {
        int s0 = srcl[p], s1 = srcl[p + 1];
        int ea = half ? s1 : s0;
        acc8p(a2, T[(size_t)ea * 32 + sub]);
    }
    if (p < pe && half == 0)
        acc8p(a2, T[(size_t)srcl[p] * 32 + sub]);

    float af8[8];
    #pragma unroll
    for (int k = 0; k < 4; ++k) {
        floatx2 t = pkadd(a2[k], c2[k]);
        af8[2 * k]     = t[0] + __shfl_xor(t[0], 32);
        af8[2 * k + 1] = t[1] + __shfl_xor(t[1], 32);
    }
    float dc = dis[node];
    const float4* cb4 = (const float4*)cb;
    const float4* g4  = (const float4*)g;
    const float4* bt4 = (const float4*)bt;
    float4 cba = cb4[sub * 2], cbb = cb4[sub * 2 + 1];
    float h[8];
    h[0] = fmaf(af8[0], dc, cba.x); h[1] = fmaf(af8[1], dc, cba.y);
    h[2] = fmaf(af8[2], dc, cba.z); h[3] = fmaf(af8[3], dc, cba.w);
    h[4] = fmaf(af8[4], dc, cbb.x); h[5] = fmaf(af8[5], dc, cbb.y);
    h[6] = fmaf(af8[6], dc, cbb.z); h[7] = fmaf(af8[7], dc, cbb.w);
    float s = 0.f, sq = 0.f;
    #pragma unroll
    for (int j = 0; j < 8; ++j) { s += h[j]; sq += h[j] * h[j]; }
    #pragma unroll
    for (int off = 1; off < 32; off <<= 1) { s += __shfl_xor(s, off); sq += __shfl_xor(sq, off); }
    float mu  = s * (1.f / 256.f);
    float var = sq * (1.f / 256.f) - mu * mu;
    float inv = rsqrtf(var + 1e-5f);
    if (half == 0) {
        float4 ga = g4[sub * 2], gb = g4[sub * 2 + 1];
        float4 ba = bt4[sub * 2], bb = bt4[sub * 2 + 1];
        float gv[8] = {ga.x, ga.y, ga.z, ga.w, gb.x, gb.y, gb.z, gb.w};
        float bv[8] = {ba.x, ba.y, ba.z, ba.w, bb.x, bb.y, bb.z, bb.w};
        unsigned short o[8];
        #pragma unroll
        for (int j = 0; j < 8; ++j)
            o[j] = f2b(fmaxf(fmaf((h[j] - mu) * inv, gv[j], bv[j]), 0.f));
        uint4 st;
        st.x = (unsigned)o[0] | ((unsigned)o[1] << 16);
        st.y = (unsigned)o[2] | ((unsigned)o[3] << 16);
        st.z = (unsigned)o[4] | ((unsigned)o[5] << 16);
        st.w = (unsigned)o[6] | ((unsigned)o[7] << 16);
        ((uint4*)hout)[(size_t)node * 32 + sub] = st;
    }
}

extern "C" void kernel_launch(void* const* d_in, const int* in_sizes, int n_in,
                              void* d_out, int out_size, void* d_ws, size_t ws_size,
                              hipStream_t stream) {
    const float* x      = (const float*)d_in[0];
    const int*   ei     = (const int*)d_in[1];     // (2,E) int32
    const float* enc_w  = (const float*)d_in[2];
    const float* enc_b  = (const float*)d_in[3];
    const float* conv_w = (const float*)d_in[4];
    const float* conv_b = (const float*)d_in[5];
    const float* ln_g   = (const float*)d_in[6];
    const float* ln_b   = (const float*)d_in[7];
    const float* w1     = (const float*)d_in[8];
    const float* b1     = (const float*)d_in[9];
    const float* w2     = (const float*)d_in[10];
    const float* b2     = (const float*)d_in[11];
    float* out = (float*)d_out;

    char* ws = (char*)d_ws;
    size_t off = 0;
    auto alloc = [&](size_t bytes) -> void* {
        void* p = ws + off;
        off = (off + bytes + 255) & ~(size_t)255;
        return p;
    };
    int*   offs  = (int*)alloc((size_t)(N_NODES + 1) * 4);
    int*   srcl  = (int*)alloc((size_t)N_EDGES * 4);
    float* dis   = (float*)alloc((size_t)N_NODES * 4);
    int*   gfill = (int*)alloc((size_t)NBUCK * 4);
    unsigned short* hb  = (unsigned short*)alloc((size_t)N_NODES * HID * 2);   // enc out / final h
    unsigned short* hwa = (unsigned short*)alloc((size_t)N_NODES * HID * 2);   // gather ping
    unsigned short* hwb = (unsigned short*)alloc((size_t)N_NODES * HID * 2);   // gather pong
    unsigned* pairs = (unsigned*)alloc((size_t)NBUCK * BCAP * 4);
    unsigned short* enc_t  = (unsigned short*)alloc((size_t)IN_C * HID * 2);
    unsigned short* conv_t = (unsigned short*)alloc((size_t)NLAYER * HID * HID * 2);
    unsigned short* lin1_t = (unsigned short*)alloc((size_t)HID * (HID / 2) * 2);

    const int* row = ei;             // sources
    const int* col = ei + N_EDGES;   // targets

    {
        int tot = IN_C * HID + NLAYER * HID * HID + HID * (HID / 2);
        k_wtz<<<(tot + 255) / 256, 256, 0, stream>>>(enc_w, conv_w, w1,
                                                     enc_t, conv_t, lin1_t, gfill, offs);
    }
    kb_scatter<<<(N_EDGES + EPB - 1) / EPB, 256, 0, stream>>>(row, col, gfill, pairs, N_EDGES);
    kb_build<<<NBUCK, 256, 0, stream>>>(pairs, gfill, offs, dis, srcl, N_NODES);

    const int gB = (N_NODES + 127) / 128;
    // encoder: hb = bf16(x @ enc_w + enc_b)
    k_mme<<<gB, 512, 0, stream>>>(x, enc_t, enc_b, hb, N_NODES);
    // hw0 = (hb @ W0) * dis
    k_mmc<<<gB, 512, 0, stream>>>(hb, conv_t, dis, hwa, N_NODES);
    // fused layers 0..2: agg+LN+ReLU then xW_{l+1}*dis
    k_fused<<<gB, 512, 0, stream>>>(hwa, srcl, offs, dis, conv_b,           ln_g,           ln_b,
                                    conv_t + (size_t)1 * HID * HID, hwb, N_NODES);
    k_fused<<<gB, 512, 0, stream>>>(hwb, srcl, offs, dis, conv_b + HID,     ln_g + HID,     ln_b + HID,
                                    conv_t + (size_t)2 * HID * HID, hwa, N_NODES);
    k_fused<<<gB, 512, 0, stream>>>(hwa, srcl, offs, dis, conv_b + 2 * HID, ln_g + 2 * HID, ln_b + 2 * HID,
                                    conv_t + (size_t)3 * HID * HID, hwb, N_NODES);
    // last layer: agg+LN+ReLU -> hb (feeds head)
    k_agg<<<(N_NODES * 64 + 255) / 256, 256, 0, stream>>>(
        hwb, srcl, offs, dis, conv_b + 3 * HID, ln_g + 3 * HID, ln_b + 3 * HID, hb, N_NODES);
    // head
    k_head<<<gB, 256, 0, stream>>>(hb, lin1_t, b1, w2, b2, out, N_NODES);
}

// Round 4
// 824.707 us; speedup vs baseline: 1.0640x; 1.0640x over previous
//
#include <hip/hip_runtime.h>

#define N_NODES 100000
#define N_EDGES 1600000
#define IN_C    128
#define HID     256
#define NLAYER  4

#define NBUCK 391     // ceil(N_NODES / 256) buckets, bucket = col >> 8
#define BCAP  8192    // padded per-bucket capacity in pairs buffer
#define EPB   4096    // edges per kb_scatter block
#define CAPL  6144    // per-bucket LDS srcl capacity in kb_build

typedef __attribute__((ext_vector_type(8))) __bf16 bf16x8;
typedef __attribute__((ext_vector_type(4))) float  floatx4;

__device__ inline unsigned short f2b(float f) {
    unsigned u = __builtin_bit_cast(unsigned, f);
    return (unsigned short)((u + 0x7fffu + ((u >> 16) & 1u)) >> 16);
}
// unpack+accumulate 8 bf16 (uint4) into fp32[8]
__device__ inline void acc8(float* a, uint4 v) {
    unsigned wds[4] = {v.x, v.y, v.z, v.w};
    #pragma unroll
    for (int k = 0; k < 4; ++k) {
        a[2*k]   += __builtin_bit_cast(float, wds[k] << 16);
        a[2*k+1] += __builtin_bit_cast(float, wds[k] & 0xffff0000u);
    }
}
// async global->LDS, 16 B per lane (lane-contiguous LDS dest required)
__device__ inline void gl16(const void* g, void* l) {
    __builtin_amdgcn_global_load_lds(
        (const __attribute__((address_space(1))) unsigned int*)g,
        (__attribute__((address_space(3))) unsigned int*)l, 16, 0, 0);
}

// ---------------- CSR build: bucket pipeline ----------------
__global__ __launch_bounds__(256) void kb_scatter(
        const int* __restrict__ row, const int* __restrict__ col,
        int* __restrict__ gfill, uint2* __restrict__ pairs, int e) {
    __shared__ uint2 ep[EPB];
    __shared__ int hist[NBUCK];
    __shared__ int lbase[NBUCK];
    const int tid  = threadIdx.x;
    const int base = blockIdx.x * EPB;
    for (int b = tid; b < NBUCK; b += 256) hist[b] = 0;
    __syncthreads();
    #pragma unroll
    for (int k = 0; k < EPB / 256; ++k) {
        int i = base + k * 256 + tid;
        uint2 pr = make_uint2(0xffffffffu, 0u);
        if (i < e) {
            pr.x = (unsigned)col[i];
            pr.y = (unsigned)row[i];
            atomicAdd(&hist[pr.x >> 8], 1);
        }
        ep[k * 256 + tid] = pr;
    }
    __syncthreads();
    for (int b = tid; b < NBUCK; b += 256) {
        int h = hist[b];
        lbase[b] = h ? atomicAdd(&gfill[b], h) : 0;
    }
    __syncthreads();
    for (int b = tid; b < NBUCK; b += 256) hist[b] = 0;
    __syncthreads();
    #pragma unroll
    for (int k = 0; k < EPB / 256; ++k) {
        uint2 pr = ep[k * 256 + tid];
        if (pr.x != 0xffffffffu) {
            int bk = pr.x >> 8;
            int p  = lbase[bk] + atomicAdd(&hist[bk], 1);
            if (p < BCAP) pairs[(size_t)bk * BCAP + p] = pr;
        }
    }
}

__global__ void kb_scan(const int* __restrict__ gfill, int* __restrict__ boff,
                        int* __restrict__ offs) {
    __shared__ int wsum[8];
    const int t = threadIdx.x, lane = t & 63, w = t >> 6;   // 512 threads
    int v = (t < NBUCK) ? gfill[t] : 0;
    int inc = v;
    #pragma unroll
    for (int o = 1; o < 64; o <<= 1) { int u = __shfl_up(inc, o); if (lane >= o) inc += u; }
    if (lane == 63) wsum[w] = inc;
    __syncthreads();
    if (t == 0) { int r = 0; for (int i = 0; i < 8; ++i) { int x = wsum[i]; wsum[i] = r; r += x; } }
    __syncthreads();
    int excl = wsum[w] + inc - v;
    if (t <= NBUCK) boff[t] = excl;
    if (t == 0) offs[N_NODES] = N_EDGES;
}

__global__ __launch_bounds__(256) void kb_build(
        const uint2* __restrict__ pairs, const int* __restrict__ gfill,
        const int* __restrict__ boff,
        int* __restrict__ offs, float* __restrict__ dis,
        int* __restrict__ srcl, int n) {
    __shared__ int lcnt[256];
    __shared__ int lstart[256];
    __shared__ int wsum[4];
    __shared__ int sl[CAPL];
    const int b = blockIdx.x;
    const int tid = threadIdx.x, lane = tid & 63, w = tid >> 6;
    int cnt = gfill[b]; if (cnt > CAPL) cnt = CAPL;
    const int base = boff[b];
    const uint2* bp = pairs + (size_t)b * BCAP;
    lcnt[tid] = 0;
    __syncthreads();
    for (int i = tid; i < cnt; i += 256)
        atomicAdd(&lcnt[bp[i].x & 255], 1);
    __syncthreads();
    int v = lcnt[tid];
    int inc = v;
    #pragma unroll
    for (int o = 1; o < 64; o <<= 1) { int u = __shfl_up(inc, o); if (lane >= o) inc += u; }
    if (lane == 63) wsum[w] = inc;
    __syncthreads();
    if (tid == 0) { int r = 0; for (int i = 0; i < 4; ++i) { int x = wsum[i]; wsum[i] = r; r += x; } }
    __syncthreads();
    int excl = wsum[w] + inc - v;
    lstart[tid] = excl;
    int node = (b << 8) + tid;
    if (node < n) {
        dis[node]  = rsqrtf((float)(v + 1));   // +1 self-loop
        offs[node] = base + excl;
    }
    __syncthreads();
    lcnt[tid] = 0;   // reuse as fill counters
    __syncthreads();
    for (int i = tid; i < cnt; i += 256) {
        uint2 pr = bp[i];
        int c = pr.x & 255;
        int q = lstart[c] + atomicAdd(&lcnt[c], 1);
        sl[q] = (int)pr.y;
    }
    __syncthreads();
    // per-node insertion sort by source id: all resident gather waves then walk
    // the source axis in lock-step -> small instantaneous working set -> L2 hits
    {
        int s0 = lstart[tid];
        for (int i = 1; i < v; ++i) {
            int key = sl[s0 + i];
            int j = i - 1;
            while (j >= 0 && sl[s0 + j] > key) { sl[s0 + j + 1] = sl[s0 + j]; --j; }
            sl[s0 + j + 1] = key;
        }
    }
    __syncthreads();
    for (int i = tid; i < cnt; i += 256)
        srcl[base + i] = sl[i];
}

// ---------------- merged: zero gfill + weight transpose/convert ----------------
__global__ void k_wtz(const float* __restrict__ enc_w, const float* __restrict__ conv_w,
                      const float* __restrict__ w1,
                      unsigned short* __restrict__ enc_t, unsigned short* __restrict__ conv_t,
                      unsigned short* __restrict__ lin1_t, int* __restrict__ gfill) {
    int idx = blockIdx.x * blockDim.x + threadIdx.x;
    if (idx < NBUCK) gfill[idx] = 0;
    if (idx < IN_C * HID) {
        int k = idx / HID, n = idx % HID;
        enc_t[n * IN_C + k] = f2b(enc_w[idx]);
    } else if (idx < IN_C * HID + NLAYER * HID * HID) {
        int r = idx - IN_C * HID;
        int l = r / (HID * HID);
        int e = r % (HID * HID);
        int k = e / HID, n = e % HID;
        conv_t[(size_t)l * HID * HID + n * HID + k] = f2b(conv_w[r]);
    } else if (idx < IN_C * HID + NLAYER * HID * HID + HID * (HID / 2)) {
        int e = idx - (IN_C * HID + NLAYER * HID * HID);
        int k = e / (HID / 2), n = e % (HID / 2);
        lin1_t[n * HID + k] = f2b(w1[e]);
    }
}

// ---------------- encoder GEMM: hb = bf16(x(fp32) @ enc_t^T + bias) ----------------
// BN=256 full-width tile, 512 threads / 8 waves (wave tile 64x64): A panel read once
__global__ __launch_bounds__(512) void k_mme(
        const float* __restrict__ Af,
        const unsigned short* __restrict__ Wt,     // [256][128]
        const float* __restrict__ bias,
        unsigned short* __restrict__ Cout, int M) {
    const int K = IN_C;                            // 128
    __shared__ unsigned short As[128 * 32];
    __shared__ unsigned short Bs[256 * 32];
    const int tid  = threadIdx.x;
    const int lane = tid & 63;
    const int w    = tid >> 6;
    const int bm   = blockIdx.x * 128;

    const int r0 = tid >> 2, q0 = tid & 3;
    const int a_off  = min(bm + r0, M - 1) * K + q0 * 8;
    const int b_off0 = r0 * K + q0 * 8;            // rows 0..127 of Wt
    const int b_off1 = (r0 + 128) * K + q0 * 8;    // rows 128..255

    floatx4 acc[4][4];
    #pragma unroll
    for (int i = 0; i < 4; ++i)
        #pragma unroll
        for (int j = 0; j < 4; ++j)
            acc[i][j] = (floatx4){0.f, 0.f, 0.f, 0.f};

    const int wm = (w & 1) * 64;
    const int wn = (w >> 1) * 64;
    const int fm = lane & 15;
    const int fq = (lane >> 4) * 8;

    uint4 ra;
    auto loadA = [&](int koff, uint4& oa) {
        float4 f0 = *(const float4*)(Af + a_off + koff);
        float4 f1 = *(const float4*)(Af + a_off + koff + 4);
        oa.x = (unsigned)f2b(f0.x) | ((unsigned)f2b(f0.y) << 16);
        oa.y = (unsigned)f2b(f0.z) | ((unsigned)f2b(f0.w) << 16);
        oa.z = (unsigned)f2b(f1.x) | ((unsigned)f2b(f1.y) << 16);
        oa.w = (unsigned)f2b(f1.z) | ((unsigned)f2b(f1.w) << 16);
    };

    loadA(0, ra);

    const int KT = K >> 5;   // 4
    for (int kt = 0; kt < KT; ++kt) {
        int k0 = kt << 5;
        ((uint4*)As)[tid] = ra;
        gl16(Wt + b_off0 + k0, Bs + (size_t)tid * 8);
        gl16(Wt + b_off1 + k0, Bs + (size_t)(tid + 512) * 8);
        __syncthreads();
        if (kt + 1 < KT) loadA((kt + 1) << 5, ra);
        bf16x8 af[4], bfr[4];
        #pragma unroll
        for (int i = 0; i < 4; ++i)
            af[i] = *(const bf16x8*)(const void*)(As + (wm + i * 16 + fm) * 32 + fq);
        #pragma unroll
        for (int j = 0; j < 4; ++j)
            bfr[j] = *(const bf16x8*)(const void*)(Bs + (wn + j * 16 + fm) * 32 + fq);
        #pragma unroll
        for (int i = 0; i < 4; ++i)
            #pragma unroll
            for (int j = 0; j < 4; ++j)
                acc[i][j] = __builtin_amdgcn_mfma_f32_16x16x32_bf16(af[i], bfr[j], acc[i][j], 0, 0, 0);
        __syncthreads();
    }

    const int quad = lane >> 4;
    #pragma unroll
    for (int i = 0; i < 4; ++i) {
        #pragma unroll
        for (int r = 0; r < 4; ++r) {
            int row = bm + wm + i * 16 + quad * 4 + r;
            if (row >= M) continue;
            #pragma unroll
            for (int j = 0; j < 4; ++j) {
                int colg = wn + j * 16 + fm;
                float v = acc[i][j][r] + bias[colg];
                Cout[(size_t)row * HID + colg] = f2b(v);
            }
        }
    }
}

// ---------------- conv GEMM (bf16): hw = bf16((h @ W) * scale[row]) ----------------
// BN=256 full-width tile, 512 threads / 8 waves: A panel fetched exactly once
__global__ __launch_bounds__(512) void k_mmc(
        const unsigned short* __restrict__ A,      // [M][256] bf16
        const unsigned short* __restrict__ Wt,     // [256][256] bf16
        const float* __restrict__ scale,
        unsigned short* __restrict__ Cout, int M) {
    const int K = HID;                             // 256
    __shared__ unsigned short As[128 * 32];
    __shared__ unsigned short Bs[256 * 32];
    const int tid  = threadIdx.x;
    const int lane = tid & 63;
    const int w    = tid >> 6;
    const int bm   = blockIdx.x * 128;

    const int r0 = tid >> 2, q0 = tid & 3;
    const int a_off  = min(bm + r0, M - 1) * K + q0 * 8;
    const int b_off0 = r0 * K + q0 * 8;
    const int b_off1 = (r0 + 128) * K + q0 * 8;

    floatx4 acc[4][4];
    #pragma unroll
    for (int i = 0; i < 4; ++i)
        #pragma unroll
        for (int j = 0; j < 4; ++j)
            acc[i][j] = (floatx4){0.f, 0.f, 0.f, 0.f};

    const int wm = (w & 1) * 64;
    const int wn = (w >> 1) * 64;
    const int fm = lane & 15;
    const int fq = (lane >> 4) * 8;

    for (int kt = 0; kt < 8; ++kt) {
        int k0 = kt << 5;
        gl16(A  + a_off  + k0, As + (size_t)tid * 8);
        gl16(Wt + b_off0 + k0, Bs + (size_t)tid * 8);
        gl16(Wt + b_off1 + k0, Bs + (size_t)(tid + 512) * 8);
        __syncthreads();
        bf16x8 af[4], bfr[4];
        #pragma unroll
        for (int i = 0; i < 4; ++i)
            af[i] = *(const bf16x8*)(const void*)(As + (wm + i * 16 + fm) * 32 + fq);
        #pragma unroll
        for (int j = 0; j < 4; ++j)
            bfr[j] = *(const bf16x8*)(const void*)(Bs + (wn + j * 16 + fm) * 32 + fq);
        #pragma unroll
        for (int i = 0; i < 4; ++i)
            #pragma unroll
            for (int j = 0; j < 4; ++j)
                acc[i][j] = __builtin_amdgcn_mfma_f32_16x16x32_bf16(af[i], bfr[j], acc[i][j], 0, 0, 0);
        __syncthreads();
    }

    const int quad = lane >> 4;
    #pragma unroll
    for (int i = 0; i < 4; ++i) {
        #pragma unroll
        for (int r = 0; r < 4; ++r) {
            int row = bm + wm + i * 16 + quad * 4 + r;
            if (row >= M) continue;
            float sc = scale[row];
            #pragma unroll
            for (int j = 0; j < 4; ++j) {
                int colg = wn + j * 16 + fm;
                Cout[(size_t)row * HID + colg] = f2b(acc[i][j][r] * sc);
            }
        }
    }
}

// ---------------- fused head: out = relu(h@w1+b1)@w2 + b2 ----------------
__global__ __launch_bounds__(256) void k_head(
        const unsigned short* __restrict__ A,     // h bf16 [M,256]
        const unsigned short* __restrict__ Wt,    // lin1^T bf16 [128][256]
        const float* __restrict__ b1, const float* __restrict__ w2,
        const float* __restrict__ b2, float* __restrict__ out, int M) {
    const int K = 256;
    __shared__ unsigned short As[128 * 32];
    __shared__ unsigned short Bs[128 * 32];
    const int tid  = threadIdx.x;
    const int lane = tid & 63;
    const int w    = tid >> 6;
    const int bm   = blockIdx.x * 128;

    const int i0 = tid, i1 = tid + 256;
    const int r0 = i0 >> 2, r1 = i1 >> 2;
    const int q0 = i0 & 3,  q1 = i1 & 3;
    const int a_off0 = min(bm + r0, M - 1) * K + q0 * 8;
    const int a_off1 = min(bm + r1, M - 1) * K + q1 * 8;
    const int b_off0 = r0 * K + q0 * 8;
    const int b_off1 = r1 * K + q1 * 8;

    floatx4 acc[4][4];
    #pragma unroll
    for (int i = 0; i < 4; ++i)
        #pragma unroll
        for (int j = 0; j < 4; ++j)
            acc[i][j] = (floatx4){0.f, 0.f, 0.f, 0.f};

    const int wm = (w & 1) * 64;
    const int wn = (w >> 1) * 64;
    const int fm = lane & 15;
    const int fq = (lane >> 4) * 8;

    for (int kt = 0; kt < 8; ++kt) {
        int k0 = kt << 5;
        gl16(A  + a_off0 + k0, As + (size_t)i0 * 8);
        gl16(A  + a_off1 + k0, As + (size_t)i1 * 8);
        gl16(Wt + b_off0 + k0, Bs + (size_t)i0 * 8);
        gl16(Wt + b_off1 + k0, Bs + (size_t)i1 * 8);
        __syncthreads();
        bf16x8 af[4], bfr[4];
        #pragma unroll
        for (int i = 0; i < 4; ++i)
            af[i] = *(const bf16x8*)(const void*)(As + (wm + i * 16 + fm) * 32 + fq);
        #pragma unroll
        for (int j = 0; j < 4; ++j)
            bfr[j] = *(const bf16x8*)(const void*)(Bs + (wn + j * 16 + fm) * 32 + fq);
        #pragma unroll
        for (int i = 0; i < 4; ++i)
            #pragma unroll
            for (int j = 0; j < 4; ++j)
                acc[i][j] = __builtin_amdgcn_mfma_f32_16x16x32_bf16(af[i], bfr[j], acc[i][j], 0, 0, 0);
        __syncthreads();
    }

    // epilogue: relu(acc + b1) dot w2, reduce into out
    float* red = (float*)As;   // 256 floats, safe after final barrier
    const int q = lane >> 4;
    float b1v[4], w2v[4];
    #pragma unroll
    for (int j = 0; j < 4; ++j) {
        int col = wn + j * 16 + fm;
        b1v[j] = b1[col]; w2v[j] = w2[col];
    }
    #pragma unroll
    for (int i = 0; i < 4; ++i) {
        #pragma unroll
        for (int r = 0; r < 4; ++r) {
            float s = 0.f;
            #pragma unroll
            for (int j = 0; j < 4; ++j)
                s += fmaxf(acc[i][j][r] + b1v[j], 0.f) * w2v[j];
            #pragma unroll
            for (int off = 1; off < 16; off <<= 1) s += __shfl_xor(s, off);
            if (fm == 0) {
                int m = wm + i * 16 + q * 4 + r;
                red[m * 2 + (wn >> 6)] = s;
            }
        }
    }
    __syncthreads();
    if (tid < 128) {
        int row = bm + tid;
        if (row < M) out[row] = red[tid * 2] + red[tid * 2 + 1] + b2[0];
    }
}

// ---------------- aggregation + bias + LayerNorm + ReLU, one wave per node ----------------
// 2 edges per wave (lanes 0-31 / 32-63), 16B/lane; scalar index loads; 8-edge unroll
__global__ void k_agg(const unsigned short* __restrict__ hw, const int* __restrict__ srcl,
                      const int* __restrict__ offs, const float* __restrict__ dis,
                      const float* __restrict__ cb, const float* __restrict__ g,
                      const float* __restrict__ bt, unsigned short* __restrict__ hout, int n) {
    int gtid = blockIdx.x * blockDim.x + threadIdx.x;
    int node = __builtin_amdgcn_readfirstlane(gtid >> 6);   // grid sized so node < n always
    int lane = threadIdx.x & 63;
    const int half = lane >> 5;
    const int sub  = lane & 31;
    const uint4* T = (const uint4*)hw;    // row = 32 x uint4 (512 B)

    float a[8] = {0,0,0,0,0,0,0,0};
    float c[8] = {0,0,0,0,0,0,0,0};
    if (half == 0) {
        uint4 v = T[(size_t)node * 32 + sub];   // self-loop (pre-scaled by dis[src])
        acc8(a, v);
    }
    int p = offs[node], pe = offs[node + 1];
    for (; p + 7 < pe; p += 8) {
        int s0 = srcl[p],     s1 = srcl[p + 1], s2 = srcl[p + 2], s3 = srcl[p + 3];
        int s4 = srcl[p + 4], s5 = srcl[p + 5], s6 = srcl[p + 6], s7 = srcl[p + 7];
        int ea = half ? s1 : s0;
        int eb = half ? s3 : s2;
        int ec = half ? s5 : s4;
        int ed = half ? s7 : s6;
        uint4 va = T[(size_t)ea * 32 + sub];
        uint4 vb = T[(size_t)eb * 32 + sub];
        uint4 vc = T[(size_t)ec * 32 + sub];
        uint4 vd = T[(size_t)ed * 32 + sub];
        acc8(a, va);
        acc8(c, vb);
        acc8(a, vc);
        acc8(c, vd);
    }
    for (; p + 1 < pe; p += 2) {
        int s0 = srcl[p], s1 = srcl[p + 1];
        int ea = half ? s1 : s0;
        uint4 v = T[(size_t)ea * 32 + sub];
        acc8(a, v);
    }
    if (p < pe && half == 0) {
        int s0 = srcl[p];
        uint4 v = T[(size_t)s0 * 32 + sub];
        acc8(a, v);
    }
    #pragma unroll
    for (int j = 0; j < 8; ++j) {
        a[j] += c[j];
        a[j] += __shfl_xor(a[j], 32);   // combine edge-parity halves
    }
    // lanes 0-31 (and duplicated 32-63) now hold the full aggregate; features f = sub*8+j
    float dc = dis[node];
    const float4* cb4 = (const float4*)cb;
    const float4* g4  = (const float4*)g;
    const float4* bt4 = (const float4*)bt;
    float4 cba = cb4[sub * 2], cbb = cb4[sub * 2 + 1];
    float h[8];
    h[0] = fmaf(a[0], dc, cba.x); h[1] = fmaf(a[1], dc, cba.y);
    h[2] = fmaf(a[2], dc, cba.z); h[3] = fmaf(a[3], dc, cba.w);
    h[4] = fmaf(a[4], dc, cbb.x); h[5] = fmaf(a[5], dc, cbb.y);
    h[6] = fmaf(a[6], dc, cbb.z); h[7] = fmaf(a[7], dc, cbb.w);
    float s = 0.f, sq = 0.f;
    #pragma unroll
    for (int j = 0; j < 8; ++j) { s += h[j]; sq += h[j] * h[j]; }
    #pragma unroll
    for (int off = 1; off < 32; off <<= 1) { s += __shfl_xor(s, off); sq += __shfl_xor(sq, off); }
    float mu  = s * (1.f / 256.f);
    float var = sq * (1.f / 256.f) - mu * mu;
    float inv = rsqrtf(var + 1e-5f);
    if (half == 0) {
        float4 ga = g4[sub * 2], gb = g4[sub * 2 + 1];
        float4 ba = bt4[sub * 2], bb = bt4[sub * 2 + 1];
        float gv[8] = {ga.x, ga.y, ga.z, ga.w, gb.x, gb.y, gb.z, gb.w};
        float bv[8] = {ba.x, ba.y, ba.z, ba.w, bb.x, bb.y, bb.z, bb.w};
        unsigned short o[8];
        #pragma unroll
        for (int j = 0; j < 8; ++j)
            o[j] = f2b(fmaxf(fmaf((h[j] - mu) * inv, gv[j], bv[j]), 0.f));
        uint4 st;
        st.x = (unsigned)o[0] | ((unsigned)o[1] << 16);
        st.y = (unsigned)o[2] | ((unsigned)o[3] << 16);
        st.z = (unsigned)o[4] | ((unsigned)o[5] << 16);
        st.w = (unsigned)o[6] | ((unsigned)o[7] << 16);
        ((uint4*)hout)[(size_t)node * 32 + sub] = st;
    }
}

extern "C" void kernel_launch(void* const* d_in, const int* in_sizes, int n_in,
                              void* d_out, int out_size, void* d_ws, size_t ws_size,
                              hipStream_t stream) {
    const float* x      = (const float*)d_in[0];
    const int*   ei     = (const int*)d_in[1];     // (2,E) int32
    const float* enc_w  = (const float*)d_in[2];
    const float* enc_b  = (const float*)d_in[3];
    const float* conv_w = (const float*)d_in[4];
    const float* conv_b = (const float*)d_in[5];
    const float* ln_g   = (const float*)d_in[6];
    const float* ln_b   = (const float*)d_in[7];
    const float* w1     = (const float*)d_in[8];
    const float* b1     = (const float*)d_in[9];
    const float* w2     = (const float*)d_in[10];
    const float* b2     = (const float*)d_in[11];
    float* out = (float*)d_out;

    char* ws = (char*)d_ws;
    size_t off = 0;
    auto alloc = [&](size_t bytes) -> void* {
        void* p = ws + off;
        off = (off + bytes + 255) & ~(size_t)255;
        return p;
    };
    int*   offs  = (int*)alloc((size_t)(N_NODES + 1) * 4);
    int*   srcl  = (int*)alloc((size_t)N_EDGES * 4);
    float* dis   = (float*)alloc((size_t)N_NODES * 4);
    int*   gfill = (int*)alloc((size_t)NBUCK * 4);
    int*   boff  = (int*)alloc((size_t)(NBUCK + 1) * 4);
    unsigned short* hb = (unsigned short*)alloc((size_t)N_NODES * HID * 2);   // h, bf16
    unsigned short* hw = (unsigned short*)alloc((size_t)N_NODES * HID * 2);   // hw, bf16
    uint2* pairs = (uint2*)alloc((size_t)NBUCK * BCAP * 8);
    unsigned short* enc_t  = (unsigned short*)alloc((size_t)IN_C * HID * 2);
    unsigned short* conv_t = (unsigned short*)alloc((size_t)NLAYER * HID * HID * 2);
    unsigned short* lin1_t = (unsigned short*)alloc((size_t)HID * (HID / 2) * 2);

    const int* row = ei;             // sources
    const int* col = ei + N_EDGES;   // targets

    // ---- weight conversion + gfill zero (merged), then CSR bucket pipeline ----
    {
        int tot = IN_C * HID + NLAYER * HID * HID + HID * (HID / 2);
        k_wtz<<<(tot + 255) / 256, 256, 0, stream>>>(enc_w, conv_w, w1,
                                                     enc_t, conv_t, lin1_t, gfill);
    }
    kb_scatter<<<(N_EDGES + EPB - 1) / EPB, 256, 0, stream>>>(row, col, gfill, pairs, N_EDGES);
    kb_scan<<<1, 512, 0, stream>>>(gfill, boff, offs);
    kb_build<<<NBUCK, 256, 0, stream>>>(pairs, gfill, boff, offs, dis, srcl, N_NODES);

    // encoder: h0 = bf16(x @ enc_w + enc_b)  -- unscaled; conv GEMM applies dis[row]
    k_mme<<<(N_NODES + 127) / 128, 512, 0, stream>>>(x, enc_t, enc_b, hb, N_NODES);

    for (int l = 0; l < NLAYER; ++l) {
        // hw = (h @ conv_w[l]) * dis[row]  (source pre-scale for the gather)
        k_mmc<<<(N_NODES + 127) / 128, 512, 0, stream>>>(
            hb, conv_t + (size_t)l * HID * HID, dis, hw, N_NODES);
        k_agg<<<(N_NODES * 64 + 255) / 256, 256, 0, stream>>>(
            hw, srcl, offs, dis, conv_b + l * HID, ln_g + l * HID, ln_b + l * HID, hb, N_NODES);
    }

    // fused head: out = relu(h@w1+b1)@w2 + b2
    k_head<<<(N_NODES + 127) / 128, 256, 0, stream>>>(hb, lin1_t, b1, w2, b2, out, N_NODES);
}

// Round 5
// 779.569 us; speedup vs baseline: 1.1256x; 1.0579x over previous
//
#include <hip/hip_runtime.h>

#define N_NODES 100000
#define N_EDGES 1600000
#define IN_C    128
#define HID     256
#define NLAYER  4

#define NBUCK 391     // ceil(N_NODES / 256) buckets, bucket = col >> 8
#define BCAP  8192    // padded per-bucket capacity in pairs buffer
#define EPB   4096    // edges per kb_scatter block
#define CAPL  6144    // per-bucket LDS srcl capacity in kb_build

typedef __attribute__((ext_vector_type(8))) __bf16 bf16x8;
typedef __attribute__((ext_vector_type(4))) float  floatx4;

__device__ inline unsigned short f2b(float f) {
    unsigned u = __builtin_bit_cast(unsigned, f);
    return (unsigned short)((u + 0x7fffu + ((u >> 16) & 1u)) >> 16);
}
// unpack+accumulate 8 bf16 (uint4) into fp32[8]
__device__ inline void acc8(float* a, uint4 v) {
    unsigned wds[4] = {v.x, v.y, v.z, v.w};
    #pragma unroll
    for (int k = 0; k < 4; ++k) {
        a[2*k]   += __builtin_bit_cast(float, wds[k] << 16);
        a[2*k+1] += __builtin_bit_cast(float, wds[k] & 0xffff0000u);
    }
}
// async global->LDS, 16 B per lane (lane-contiguous LDS dest required)
__device__ inline void gl16(const void* g, void* l) {
    __builtin_amdgcn_global_load_lds(
        (const __attribute__((address_space(1))) unsigned int*)g,
        (__attribute__((address_space(3))) unsigned int*)l, 16, 0, 0);
}

// ---------------- CSR build: bucket pipeline ----------------
__global__ __launch_bounds__(256) void kb_scatter(
        const int* __restrict__ row, const int* __restrict__ col,
        int* __restrict__ gfill, uint2* __restrict__ pairs, int e) {
    __shared__ uint2 ep[EPB];
    __shared__ int hist[NBUCK];
    __shared__ int lbase[NBUCK];
    const int tid  = threadIdx.x;
    const int base = blockIdx.x * EPB;
    for (int b = tid; b < NBUCK; b += 256) hist[b] = 0;
    __syncthreads();
    #pragma unroll
    for (int k = 0; k < EPB / 256; ++k) {
        int i = base + k * 256 + tid;
        uint2 pr = make_uint2(0xffffffffu, 0u);
        if (i < e) {
            pr.x = (unsigned)col[i];
            pr.y = (unsigned)row[i];
            atomicAdd(&hist[pr.x >> 8], 1);
        }
        ep[k * 256 + tid] = pr;
    }
    __syncthreads();
    for (int b = tid; b < NBUCK; b += 256) {
        int h = hist[b];
        lbase[b] = h ? atomicAdd(&gfill[b], h) : 0;
    }
    __syncthreads();
    for (int b = tid; b < NBUCK; b += 256) hist[b] = 0;
    __syncthreads();
    #pragma unroll
    for (int k = 0; k < EPB / 256; ++k) {
        uint2 pr = ep[k * 256 + tid];
        if (pr.x != 0xffffffffu) {
            int bk = pr.x >> 8;
            int p  = lbase[bk] + atomicAdd(&hist[bk], 1);
            if (p < BCAP) pairs[(size_t)bk * BCAP + p] = pr;
        }
    }
}

__global__ void kb_scan(const int* __restrict__ gfill, int* __restrict__ boff,
                        int* __restrict__ offs) {
    __shared__ int wsum[8];
    const int t = threadIdx.x, lane = t & 63, w = t >> 6;   // 512 threads
    int v = (t < NBUCK) ? gfill[t] : 0;
    int inc = v;
    #pragma unroll
    for (int o = 1; o < 64; o <<= 1) { int u = __shfl_up(inc, o); if (lane >= o) inc += u; }
    if (lane == 63) wsum[w] = inc;
    __syncthreads();
    if (t == 0) { int r = 0; for (int i = 0; i < 8; ++i) { int x = wsum[i]; wsum[i] = r; r += x; } }
    __syncthreads();
    int excl = wsum[w] + inc - v;
    if (t <= NBUCK) boff[t] = excl;
    if (t == 0) offs[N_NODES] = N_EDGES;
}

__global__ __launch_bounds__(256) void kb_build(
        const uint2* __restrict__ pairs, const int* __restrict__ gfill,
        const int* __restrict__ boff,
        int* __restrict__ offs, float* __restrict__ dis,
        int* __restrict__ srcl, int n) {
    __shared__ int lcnt[256];
    __shared__ int lstart[256];
    __shared__ int wsum[4];
    __shared__ int sl[CAPL];
    const int b = blockIdx.x;
    const int tid = threadIdx.x, lane = tid & 63, w = tid >> 6;
    int cnt = gfill[b]; if (cnt > CAPL) cnt = CAPL;
    const int base = boff[b];
    const uint2* bp = pairs + (size_t)b * BCAP;
    lcnt[tid] = 0;
    __syncthreads();
    for (int i = tid; i < cnt; i += 256)
        atomicAdd(&lcnt[bp[i].x & 255], 1);
    __syncthreads();
    int v = lcnt[tid];
    int inc = v;
    #pragma unroll
    for (int o = 1; o < 64; o <<= 1) { int u = __shfl_up(inc, o); if (lane >= o) inc += u; }
    if (lane == 63) wsum[w] = inc;
    __syncthreads();
    if (tid == 0) { int r = 0; for (int i = 0; i < 4; ++i) { int x = wsum[i]; wsum[i] = r; r += x; } }
    __syncthreads();
    int excl = wsum[w] + inc - v;
    lstart[tid] = excl;
    int node = (b << 8) + tid;
    if (node < n) {
        dis[node]  = rsqrtf((float)(v + 1));   // +1 self-loop
        offs[node] = base + excl;
    }
    __syncthreads();
    lcnt[tid] = 0;   // reuse as fill counters
    __syncthreads();
    for (int i = tid; i < cnt; i += 256) {
        uint2 pr = bp[i];
        int c = pr.x & 255;
        int q = lstart[c] + atomicAdd(&lcnt[c], 1);
        sl[q] = (int)pr.y;
    }
    __syncthreads();
    for (int i = tid; i < cnt; i += 256)
        srcl[base + i] = sl[i];
}

// ---------------- merged: zero gfill + weight transpose/convert ----------------
__global__ void k_wtz(const float* __restrict__ enc_w, const float* __restrict__ conv_w,
                      const float* __restrict__ w1,
                      unsigned short* __restrict__ enc_t, unsigned short* __restrict__ conv_t,
                      unsigned short* __restrict__ lin1_t, int* __restrict__ gfill) {
    int idx = blockIdx.x * blockDim.x + threadIdx.x;
    if (idx < NBUCK) gfill[idx] = 0;
    if (idx < IN_C * HID) {
        int k = idx / HID, n = idx % HID;
        enc_t[n * IN_C + k] = f2b(enc_w[idx]);
    } else if (idx < IN_C * HID + NLAYER * HID * HID) {
        int r = idx - IN_C * HID;
        int l = r / (HID * HID);
        int e = r % (HID * HID);
        int k = e / HID, n = e % HID;
        conv_t[(size_t)l * HID * HID + n * HID + k] = f2b(conv_w[r]);
    } else if (idx < IN_C * HID + NLAYER * HID * HID + HID * (HID / 2)) {
        int e = idx - (IN_C * HID + NLAYER * HID * HID);
        int k = e / (HID / 2), n = e % (HID / 2);
        lin1_t[n * HID + k] = f2b(w1[e]);
    }
}

// ---------------- encoder GEMM: hb = bf16(x(fp32) @ enc_t^T + bias) ----------------
// BN=256 full-width tile, 512 threads / 8 waves (wave tile 64x64): A panel read once
__global__ __launch_bounds__(512) void k_mme(
        const float* __restrict__ Af,
        const unsigned short* __restrict__ Wt,     // [256][128]
        const float* __restrict__ bias,
        unsigned short* __restrict__ Cout, int M) {
    const int K = IN_C;                            // 128
    __shared__ unsigned short As[128 * 32];
    __shared__ unsigned short Bs[256 * 32];
    const int tid  = threadIdx.x;
    const int lane = tid & 63;
    const int w    = tid >> 6;
    const int bm   = blockIdx.x * 128;

    const int r0 = tid >> 2, q0 = tid & 3;
    const int a_off  = min(bm + r0, M - 1) * K + q0 * 8;
    const int b_off0 = r0 * K + q0 * 8;            // rows 0..127 of Wt
    const int b_off1 = (r0 + 128) * K + q0 * 8;    // rows 128..255

    floatx4 acc[4][4];
    #pragma unroll
    for (int i = 0; i < 4; ++i)
        #pragma unroll
        for (int j = 0; j < 4; ++j)
            acc[i][j] = (floatx4){0.f, 0.f, 0.f, 0.f};

    const int wm = (w & 1) * 64;
    const int wn = (w >> 1) * 64;
    const int fm = lane & 15;
    const int fq = (lane >> 4) * 8;

    uint4 ra;
    auto loadA = [&](int koff, uint4& oa) {
        float4 f0 = *(const float4*)(Af + a_off + koff);
        float4 f1 = *(const float4*)(Af + a_off + koff + 4);
        oa.x = (unsigned)f2b(f0.x) | ((unsigned)f2b(f0.y) << 16);
        oa.y = (unsigned)f2b(f0.z) | ((unsigned)f2b(f0.w) << 16);
        oa.z = (unsigned)f2b(f1.x) | ((unsigned)f2b(f1.y) << 16);
        oa.w = (unsigned)f2b(f1.z) | ((unsigned)f2b(f1.w) << 16);
    };

    loadA(0, ra);

    const int KT = K >> 5;   // 4
    for (int kt = 0; kt < KT; ++kt) {
        int k0 = kt << 5;
        ((uint4*)As)[tid] = ra;
        gl16(Wt + b_off0 + k0, Bs + (size_t)tid * 8);
        gl16(Wt + b_off1 + k0, Bs + (size_t)(tid + 512) * 8);
        __syncthreads();
        if (kt + 1 < KT) loadA((kt + 1) << 5, ra);
        bf16x8 af[4], bfr[4];
        #pragma unroll
        for (int i = 0; i < 4; ++i)
            af[i] = *(const bf16x8*)(const void*)(As + (wm + i * 16 + fm) * 32 + fq);
        #pragma unroll
        for (int j = 0; j < 4; ++j)
            bfr[j] = *(const bf16x8*)(const void*)(Bs + (wn + j * 16 + fm) * 32 + fq);
        #pragma unroll
        for (int i = 0; i < 4; ++i)
            #pragma unroll
            for (int j = 0; j < 4; ++j)
                acc[i][j] = __builtin_amdgcn_mfma_f32_16x16x32_bf16(af[i], bfr[j], acc[i][j], 0, 0, 0);
        __syncthreads();
    }

    const int quad = lane >> 4;
    #pragma unroll
    for (int i = 0; i < 4; ++i) {
        #pragma unroll
        for (int r = 0; r < 4; ++r) {
            int row = bm + wm + i * 16 + quad * 4 + r;
            if (row >= M) continue;
            #pragma unroll
            for (int j = 0; j < 4; ++j) {
                int colg = wn + j * 16 + fm;
                float v = acc[i][j][r] + bias[colg];
                Cout[(size_t)row * HID + colg] = f2b(v);
            }
        }
    }
}

// ---------------- conv GEMM (bf16): hw = bf16((h @ W) * scale[row]) ----------------
// BN=256 full-width tile, 512 threads / 8 waves: A panel fetched exactly once
__global__ __launch_bounds__(512) void k_mmc(
        const unsigned short* __restrict__ A,      // [M][256] bf16
        const unsigned short* __restrict__ Wt,     // [256][256] bf16
        const float* __restrict__ scale,
        unsigned short* __restrict__ Cout, int M) {
    const int K = HID;                             // 256
    __shared__ unsigned short As[128 * 32];
    __shared__ unsigned short Bs[256 * 32];
    const int tid  = threadIdx.x;
    const int lane = tid & 63;
    const int w    = tid >> 6;
    const int bm   = blockIdx.x * 128;

    const int r0 = tid >> 2, q0 = tid & 3;
    const int a_off  = min(bm + r0, M - 1) * K + q0 * 8;
    const int b_off0 = r0 * K + q0 * 8;
    const int b_off1 = (r0 + 128) * K + q0 * 8;

    floatx4 acc[4][4];
    #pragma unroll
    for (int i = 0; i < 4; ++i)
        #pragma unroll
        for (int j = 0; j < 4; ++j)
            acc[i][j] = (floatx4){0.f, 0.f, 0.f, 0.f};

    const int wm = (w & 1) * 64;
    const int wn = (w >> 1) * 64;
    const int fm = lane & 15;
    const int fq = (lane >> 4) * 8;

    for (int kt = 0; kt < 8; ++kt) {
        int k0 = kt << 5;
        gl16(A  + a_off  + k0, As + (size_t)tid * 8);
        gl16(Wt + b_off0 + k0, Bs + (size_t)tid * 8);
        gl16(Wt + b_off1 + k0, Bs + (size_t)(tid + 512) * 8);
        __syncthreads();
        bf16x8 af[4], bfr[4];
        #pragma unroll
        for (int i = 0; i < 4; ++i)
            af[i] = *(const bf16x8*)(const void*)(As + (wm + i * 16 + fm) * 32 + fq);
        #pragma unroll
        for (int j = 0; j < 4; ++j)
            bfr[j] = *(const bf16x8*)(const void*)(Bs + (wn + j * 16 + fm) * 32 + fq);
        #pragma unroll
        for (int i = 0; i < 4; ++i)
            #pragma unroll
            for (int j = 0; j < 4; ++j)
                acc[i][j] = __builtin_amdgcn_mfma_f32_16x16x32_bf16(af[i], bfr[j], acc[i][j], 0, 0, 0);
        __syncthreads();
    }

    const int quad = lane >> 4;
    #pragma unroll
    for (int i = 0; i < 4; ++i) {
        #pragma unroll
        for (int r = 0; r < 4; ++r) {
            int row = bm + wm + i * 16 + quad * 4 + r;
            if (row >= M) continue;
            float sc = scale[row];
            #pragma unroll
            for (int j = 0; j < 4; ++j) {
                int colg = wn + j * 16 + fm;
                Cout[(size_t)row * HID + colg] = f2b(acc[i][j][r] * sc);
            }
        }
    }
}

// ---------------- fused head: out = relu(h@w1+b1)@w2 + b2 ----------------
__global__ __launch_bounds__(256) void k_head(
        const unsigned short* __restrict__ A,     // h bf16 [M,256]
        const unsigned short* __restrict__ Wt,    // lin1^T bf16 [128][256]
        const float* __restrict__ b1, const float* __restrict__ w2,
        const float* __restrict__ b2, float* __restrict__ out, int M) {
    const int K = 256;
    __shared__ unsigned short As[128 * 32];
    __shared__ unsigned short Bs[128 * 32];
    const int tid  = threadIdx.x;
    const int lane = tid & 63;
    const int w    = tid >> 6;
    const int bm   = blockIdx.x * 128;

    const int i0 = tid, i1 = tid + 256;
    const int r0 = i0 >> 2, r1 = i1 >> 2;
    const int q0 = i0 & 3,  q1 = i1 & 3;
    const int a_off0 = min(bm + r0, M - 1) * K + q0 * 8;
    const int a_off1 = min(bm + r1, M - 1) * K + q1 * 8;
    const int b_off0 = r0 * K + q0 * 8;
    const int b_off1 = r1 * K + q1 * 8;

    floatx4 acc[4][4];
    #pragma unroll
    for (int i = 0; i < 4; ++i)
        #pragma unroll
        for (int j = 0; j < 4; ++j)
            acc[i][j] = (floatx4){0.f, 0.f, 0.f, 0.f};

    const int wm = (w & 1) * 64;
    const int wn = (w >> 1) * 64;
    const int fm = lane & 15;
    const int fq = (lane >> 4) * 8;

    for (int kt = 0; kt < 8; ++kt) {
        int k0 = kt << 5;
        gl16(A  + a_off0 + k0, As + (size_t)i0 * 8);
        gl16(A  + a_off1 + k0, As + (size_t)i1 * 8);
        gl16(Wt + b_off0 + k0, Bs + (size_t)i0 * 8);
        gl16(Wt + b_off1 + k0, Bs + (size_t)i1 * 8);
        __syncthreads();
        bf16x8 af[4], bfr[4];
        #pragma unroll
        for (int i = 0; i < 4; ++i)
            af[i] = *(const bf16x8*)(const void*)(As + (wm + i * 16 + fm) * 32 + fq);
        #pragma unroll
        for (int j = 0; j < 4; ++j)
            bfr[j] = *(const bf16x8*)(const void*)(Bs + (wn + j * 16 + fm) * 32 + fq);
        #pragma unroll
        for (int i = 0; i < 4; ++i)
            #pragma unroll
            for (int j = 0; j < 4; ++j)
                acc[i][j] = __builtin_amdgcn_mfma_f32_16x16x32_bf16(af[i], bfr[j], acc[i][j], 0, 0, 0);
        __syncthreads();
    }

    // epilogue: relu(acc + b1) dot w2, reduce into out
    float* red = (float*)As;   // 256 floats, safe after final barrier
    const int q = lane >> 4;
    float b1v[4], w2v[4];
    #pragma unroll
    for (int j = 0; j < 4; ++j) {
        int col = wn + j * 16 + fm;
        b1v[j] = b1[col]; w2v[j] = w2[col];
    }
    #pragma unroll
    for (int i = 0; i < 4; ++i) {
        #pragma unroll
        for (int r = 0; r < 4; ++r) {
            float s = 0.f;
            #pragma unroll
            for (int j = 0; j < 4; ++j)
                s += fmaxf(acc[i][j][r] + b1v[j], 0.f) * w2v[j];
            #pragma unroll
            for (int off = 1; off < 16; off <<= 1) s += __shfl_xor(s, off);
            if (fm == 0) {
                int m = wm + i * 16 + q * 4 + r;
                red[m * 2 + (wn >> 6)] = s;
            }
        }
    }
    __syncthreads();
    if (tid < 128) {
        int row = bm + tid;
        if (row < M) out[row] = red[tid * 2] + red[tid * 2 + 1] + b2[0];
    }
}

// ---------------- aggregation + bias + LayerNorm + ReLU, one wave per node ----------------
// 2 edges per wave (lanes 0-31 / 32-63), 16B/lane; scalar index loads; 8-edge unroll
__global__ void k_agg(const unsigned short* __restrict__ hw, const int* __restrict__ srcl,
                      const int* __restrict__ offs, const float* __restrict__ dis,
                      const float* __restrict__ cb, const float* __restrict__ g,
                      const float* __restrict__ bt, unsigned short* __restrict__ hout, int n) {
    int gtid = blockIdx.x * blockDim.x + threadIdx.x;
    int node = __builtin_amdgcn_readfirstlane(gtid >> 6);   // grid sized so node < n always
    int lane = threadIdx.x & 63;
    const int half = lane >> 5;
    const int sub  = lane & 31;
    const uint4* T = (const uint4*)hw;    // row = 32 x uint4 (512 B)

    float a[8] = {0,0,0,0,0,0,0,0};
    float c[8] = {0,0,0,0,0,0,0,0};
    if (half == 0) {
        uint4 v = T[(size_t)node * 32 + sub];   // self-loop (pre-scaled by dis[src])
        acc8(a, v);
    }
    int p = offs[node], pe = offs[node + 1];
    for (; p + 7 < pe; p += 8) {
        int s0 = srcl[p],     s1 = srcl[p + 1], s2 = srcl[p + 2], s3 = srcl[p + 3];
        int s4 = srcl[p + 4], s5 = srcl[p + 5], s6 = srcl[p + 6], s7 = srcl[p + 7];
        int ea = half ? s1 : s0;
        int eb = half ? s3 : s2;
        int ec = half ? s5 : s4;
        int ed = half ? s7 : s6;
        uint4 va = T[(size_t)ea * 32 + sub];
        uint4 vb = T[(size_t)eb * 32 + sub];
        uint4 vc = T[(size_t)ec * 32 + sub];
        uint4 vd = T[(size_t)ed * 32 + sub];
        acc8(a, va);
        acc8(c, vb);
        acc8(a, vc);
        acc8(c, vd);
    }
    for (; p + 1 < pe; p += 2) {
        int s0 = srcl[p], s1 = srcl[p + 1];
        int ea = half ? s1 : s0;
        uint4 v = T[(size_t)ea * 32 + sub];
        acc8(a, v);
    }
    if (p < pe && half == 0) {
        int s0 = srcl[p];
        uint4 v = T[(size_t)s0 * 32 + sub];
        acc8(a, v);
    }
    #pragma unroll
    for (int j = 0; j < 8; ++j) {
        a[j] += c[j];
        a[j] += __shfl_xor(a[j], 32);   // combine edge-parity halves
    }
    // lanes 0-31 (and duplicated 32-63) now hold the full aggregate; features f = sub*8+j
    float dc = dis[node];
    const float4* cb4 = (const float4*)cb;
    const float4* g4  = (const float4*)g;
    const float4* bt4 = (const float4*)bt;
    float4 cba = cb4[sub * 2], cbb = cb4[sub * 2 + 1];
    float h[8];
    h[0] = fmaf(a[0], dc, cba.x); h[1] = fmaf(a[1], dc, cba.y);
    h[2] = fmaf(a[2], dc, cba.z); h[3] = fmaf(a[3], dc, cba.w);
    h[4] = fmaf(a[4], dc, cbb.x); h[5] = fmaf(a[5], dc, cbb.y);
    h[6] = fmaf(a[6], dc, cbb.z); h[7] = fmaf(a[7], dc, cbb.w);
    float s = 0.f, sq = 0.f;
    #pragma unroll
    for (int j = 0; j < 8; ++j) { s += h[j]; sq += h[j] * h[j]; }
    #pragma unroll
    for (int off = 1; off < 32; off <<= 1) { s += __shfl_xor(s, off); sq += __shfl_xor(sq, off); }
    float mu  = s * (1.f / 256.f);
    float var = sq * (1.f / 256.f) - mu * mu;
    float inv = rsqrtf(var + 1e-5f);
    if (half == 0) {
        float4 ga = g4[sub * 2], gb = g4[sub * 2 + 1];
        float4 ba = bt4[sub * 2], bb = bt4[sub * 2 + 1];
        float gv[8] = {ga.x, ga.y, ga.z, ga.w, gb.x, gb.y, gb.z, gb.w};
        float bv[8] = {ba.x, ba.y, ba.z, ba.w, bb.x, bb.y, bb.z, bb.w};
        unsigned short o[8];
        #pragma unroll
        for (int j = 0; j < 8; ++j)
            o[j] = f2b(fmaxf(fmaf((h[j] - mu) * inv, gv[j], bv[j]), 0.f));
        uint4 st;
        st.x = (unsigned)o[0] | ((unsigned)o[1] << 16);
        st.y = (unsigned)o[2] | ((unsigned)o[3] << 16);
        st.z = (unsigned)o[4] | ((unsigned)o[5] << 16);
        st.w = (unsigned)o[6] | ((unsigned)o[7] << 16);
        ((uint4*)hout)[(size_t)node * 32 + sub] = st;
    }
}

extern "C" void kernel_launch(void* const* d_in, const int* in_sizes, int n_in,
                              void* d_out, int out_size, void* d_ws, size_t ws_size,
                              hipStream_t stream) {
    const float* x      = (const float*)d_in[0];
    const int*   ei     = (const int*)d_in[1];     // (2,E) int32
    const float* enc_w  = (const float*)d_in[2];
    const float* enc_b  = (const float*)d_in[3];
    const float* conv_w = (const float*)d_in[4];
    const float* conv_b = (const float*)d_in[5];
    const float* ln_g   = (const float*)d_in[6];
    const float* ln_b   = (const float*)d_in[7];
    const float* w1     = (const float*)d_in[8];
    const float* b1     = (const float*)d_in[9];
    const float* w2     = (const float*)d_in[10];
    const float* b2     = (const float*)d_in[11];
    float* out = (float*)d_out;

    char* ws = (char*)d_ws;
    size_t off = 0;
    auto alloc = [&](size_t bytes) -> void* {
        void* p = ws + off;
        off = (off + bytes + 255) & ~(size_t)255;
        return p;
    };
    int*   offs  = (int*)alloc((size_t)(N_NODES + 1) * 4);
    int*   srcl  = (int*)alloc((size_t)N_EDGES * 4);
    float* dis   = (float*)alloc((size_t)N_NODES * 4);
    int*   gfill = (int*)alloc((size_t)NBUCK * 4);
    int*   boff  = (int*)alloc((size_t)(NBUCK + 1) * 4);
    unsigned short* hb = (unsigned short*)alloc((size_t)N_NODES * HID * 2);   // h, bf16
    unsigned short* hw = (unsigned short*)alloc((size_t)N_NODES * HID * 2);   // hw, bf16
    uint2* pairs = (uint2*)alloc((size_t)NBUCK * BCAP * 8);
    unsigned short* enc_t  = (unsigned short*)alloc((size_t)IN_C * HID * 2);
    unsigned short* conv_t = (unsigned short*)alloc((size_t)NLAYER * HID * HID * 2);
    unsigned short* lin1_t = (unsigned short*)alloc((size_t)HID * (HID / 2) * 2);

    const int* row = ei;             // sources
    const int* col = ei + N_EDGES;   // targets

    // ---- weight conversion + gfill zero (merged), then CSR bucket pipeline ----
    {
        int tot = IN_C * HID + NLAYER * HID * HID + HID * (HID / 2);
        k_wtz<<<(tot + 255) / 256, 256, 0, stream>>>(enc_w, conv_w, w1,
                                                     enc_t, conv_t, lin1_t, gfill);
    }
    kb_scatter<<<(N_EDGES + EPB - 1) / EPB, 256, 0, stream>>>(row, col, gfill, pairs, N_EDGES);
    kb_scan<<<1, 512, 0, stream>>>(gfill, boff, offs);
    kb_build<<<NBUCK, 256, 0, stream>>>(pairs, gfill, boff, offs, dis, srcl, N_NODES);

    // encoder: h0 = bf16(x @ enc_w + enc_b)  -- unscaled; conv GEMM applies dis[row]
    k_mme<<<(N_NODES + 127) / 128, 512, 0, stream>>>(x, enc_t, enc_b, hb, N_NODES);

    for (int l = 0; l < NLAYER; ++l) {
        // hw = (h @ conv_w[l]) * dis[row]  (source pre-scale for the gather)
        k_mmc<<<(N_NODES + 127) / 128, 512, 0, stream>>>(
            hb, conv_t + (size_t)l * HID * HID, dis, hw, N_NODES);
        k_agg<<<(N_NODES * 64 + 255) / 256, 256, 0, stream>>>(
            hw, srcl, offs, dis, conv_b + l * HID, ln_g + l * HID, ln_b + l * HID, hb, N_NODES);
    }

    // fused head: out = relu(h@w1+b1)@w2 + b2
    k_head<<<(N_NODES + 127) / 128, 256, 0, stream>>>(hb, lin1_t, b1, w2, b2, out, N_NODES);
}